// Round 12
// baseline (136.813 us; speedup 1.0000x reference)
//
#include <hip/hip_runtime.h>
#include <hip/hip_bf16.h>
#include <hip/hip_fp16.h>

#define N_NODES 100000
#define N_EDGES 1600000
#define D 64
#define CHUNK 1024
#define NCHUNK ((N_NODES + CHUNK - 1) / CHUNK)   // 98

// ---- tier A2 multisplit parameters ----
#define NBIN 400          // bins of 250 rows
#define RPB  250          // rows per bin
#define MS_TILE 2048      // edges per multisplit block (782 blocks, fully resident)
#define MS_CAP  16        // LDS slots per bin per tile (mean 5.1)
#define SCAP 4352         // bin staging cap in bin_sort (mean 4000)

typedef float f32x4 __attribute__((ext_vector_type(4)));

template <typename T>
__device__ __forceinline__ T ntl(const T* p) { return __builtin_nontemporal_load(p); }

// ===========================================================================
// Tier A2 build
// ===========================================================================

// --- H -> fp16 (plain loads, 6250 blocks) ----------------------------------
__global__ void __launch_bounds__(256)
h2half_kernel(const float* __restrict__ H, unsigned short* __restrict__ Hh) {
    const int tid = blockIdx.x * blockDim.x + threadIdx.x;
    const int total = N_NODES * D / 4;
    if (tid >= total) return;
    const float4 f = reinterpret_cast<const float4*>(H)[tid];
    __half2 h01 = __floats2half2_rn(f.x, f.y);
    __half2 h23 = __floats2half2_rn(f.z, f.w);
    uint2 u;
    __builtin_memcpy(&u.x, &h01, 4);
    __builtin_memcpy(&u.y, &h23, 4);
    reinterpret_cast<uint2*>(Hh)[tid] = u;
}

// --- A2.1: 400-bin histogram (LDS-staged) -----------------------------------
__global__ void __launch_bounds__(256)
bin_hist_kernel(const int* __restrict__ row, int* __restrict__ binCounts) {
    __shared__ int h[NBIN];
    for (int i = threadIdx.x; i < NBIN; i += 256) h[i] = 0;
    __syncthreads();
    for (int e = blockIdx.x * blockDim.x + threadIdx.x; e < N_EDGES;
         e += gridDim.x * blockDim.x)
        atomicAdd(&h[row[e] / RPB], 1);
    __syncthreads();
    for (int i = threadIdx.x; i < NBIN; i += 256)
        atomicAdd(&binCounts[i], h[i]);
}

// --- A2.2: scan 400 bin counts -> binBase[0..NBIN], binCursor ---------------
__global__ void __launch_bounds__(512)
bin_scan_kernel(const int* __restrict__ binCounts,
                int* __restrict__ binBase, int* __restrict__ binCursor) {
    __shared__ int s[512];
    const int tid = threadIdx.x;
    const int cnt = (tid < NBIN) ? binCounts[tid] : 0;
    s[tid] = cnt;
    __syncthreads();
    for (int off = 1; off < 512; off <<= 1) {
        int t = (tid >= off) ? s[tid - off] : 0;
        __syncthreads();
        s[tid] += t;
        __syncthreads();
    }
    const int excl = s[tid] - cnt;
    if (tid < NBIN) {
        binBase[tid]   = excl;
        binCursor[tid] = excl;
        if (tid == NBIN - 1) binBase[NBIN] = s[tid];   // == N_EDGES
    }
}

// --- A2.3: multisplit — partition edges into 400 bins, LDS-buffered ---------
// 782 blocks x 2048 edges; 41.6 KB LDS -> 3 blocks/CU -> fully resident.
__global__ void __launch_bounds__(256)
multisplit_kernel(const int* __restrict__ row, const int* __restrict__ col,
                  const float* __restrict__ vals,
                  int* __restrict__ binCursor,
                  unsigned* __restrict__ tmp4, unsigned short* __restrict__ tmp2) {
    __shared__ unsigned       spay[NBIN][MS_CAP];   // 25.6 KB
    __shared__ unsigned short srow[NBIN][MS_CAP];   // 12.8 KB
    __shared__ int bcnt[NBIN];                      // 1.6 KB
    __shared__ int gb[NBIN];                        // 1.6 KB

    const int tid = threadIdx.x;
    for (int i = tid; i < NBIN; i += 256) bcnt[i] = 0;
    __syncthreads();

    const int base = blockIdx.x * MS_TILE;
    const int eEnd = min(base + MS_TILE, N_EDGES);

    #pragma unroll
    for (int j = 0; j < MS_TILE / 256; ++j) {
        const int e = base + j * 256 + tid;
        if (e < eEnd) {
            const int r = row[e];
            const int c = col[e];
            __half hv = __float2half_rn(vals[e]);       // vals >= 0 -> sign 0
            unsigned short hb;
            __builtin_memcpy(&hb, &hv, 2);
            const unsigned pk = ((unsigned)c << 15) | (hb & 0x7FFFu);
            const int bin = r / RPB;
            const unsigned short rl = (unsigned short)(r - bin * RPB);
            const int p = atomicAdd(&bcnt[bin], 1);
            if (p < MS_CAP) {
                spay[bin][p] = pk;
                srow[bin][p] = rl;
            } else {                                    // rare spill (~1e-5)
                const int g = atomicAdd(&binCursor[bin], 1);
                tmp4[g] = pk;
                tmp2[g] = rl;
            }
        }
    }
    __syncthreads();

    for (int i = tid; i < NBIN; i += 256) {
        const int c = min(bcnt[i], MS_CAP);
        gb[i] = atomicAdd(&binCursor[i], c);
    }
    __syncthreads();

    for (int i = tid; i < NBIN * MS_CAP; i += 256) {
        const int bin  = i / MS_CAP;
        const int slot = i - bin * MS_CAP;
        if (slot < min(bcnt[bin], MS_CAP)) {
            const int g = gb[bin] + slot;
            tmp4[g] = spay[bin][slot];
            tmp2[g] = srow[bin][slot];
        }
    }
}

// --- A2.4: per-bin LDS counting sort -> row_ptr + sorted pack ---------------
__global__ void __launch_bounds__(512)
bin_sort_kernel(const int* __restrict__ binBase,
                const unsigned* __restrict__ tmp4, const unsigned short* __restrict__ tmp2,
                int* __restrict__ row_ptr, unsigned* __restrict__ pack) {
    __shared__ unsigned       pay[SCAP];     // 17.4 KB
    __shared__ unsigned short rl[SCAP];      // 8.7 KB
    __shared__ int rcnt[512];
    __shared__ int rex[512];

    const int tid = threadIdx.x;
    const int b    = blockIdx.x;
    const int base = binBase[b];
    const int nb   = binBase[b + 1] - base;
    const int row0 = b * RPB;

    rcnt[tid] = 0;
    __syncthreads();

    // phase A: stage + histogram
    for (int i = tid; i < nb; i += 512) {
        const unsigned       p = tmp4[base + i];
        const unsigned short r = tmp2[base + i];
        if (i < SCAP) { pay[i] = p; rl[i] = r; }
        atomicAdd(&rcnt[r], 1);
    }
    __syncthreads();

    // phase B: exclusive scan of 250 counts
    const int cnt = rcnt[tid];
    rex[tid] = cnt;
    __syncthreads();
    for (int off = 1; off < 512; off <<= 1) {
        int t = (tid >= off) ? rex[tid - off] : 0;
        __syncthreads();
        rex[tid] += t;
        __syncthreads();
    }
    const int excl = rex[tid] - cnt;
    if (tid < RPB) row_ptr[row0 + tid] = base + excl;
    if (b == NBIN - 1 && tid == 0) row_ptr[N_NODES] = N_EDGES;
    __syncthreads();
    rcnt[tid] = excl;          // reuse as within-bin cursor
    __syncthreads();

    // phase C: scatter into sorted order (one L2 -> write-combined)
    for (int i = tid; i < nb; i += 512) {
        unsigned p; unsigned short r;
        if (i < SCAP) { p = pay[i]; r = rl[i]; }
        else          { p = tmp4[base + i]; r = tmp2[base + i]; }
        const int d = atomicAdd(&rcnt[r], 1);
        pack[base + d] = p;
    }
}

// ===========================================================================
// Fused gather-SPMM + GCNII epilogue — 32 rows/block, fp16 W in LDS
// LDS = supT 9.2 KB + Wlh 8 KB = 17.2 KB -> 8 blocks/CU (wave-slot cap)
// ===========================================================================
__device__ inline float h_from_bits(unsigned bits) {
    unsigned short us = (unsigned short)bits;
    __half h;
    __builtin_memcpy(&h, &us, 2);
    return __half2float(h);
}

__global__ void __launch_bounds__(256)
gather_gemm_kernel(const int* __restrict__ row_ptr,
                   const unsigned* __restrict__ pack,
                   const unsigned short* __restrict__ Hh,
                   const float* __restrict__ H0,
                   const float* __restrict__ W,
                   const float* __restrict__ lamda_p, const float* __restrict__ alpha_p,
                   const int* __restrict__ l_p,
                   float* __restrict__ out) {
    __shared__ float  supT[D][36];   // 9.2 KB: 32 rows + 4 pad
    __shared__ __half Wlh[D][D];     // 8 KB

    const int tid = threadIdx.x;
    for (int i = tid; i < D * D; i += 256)
        ((__half*)Wlh)[i] = __float2half_rn(W[i]);

    const float alpha = alpha_p[0];
    const float beta  = logf(lamda_p[0] / (float)l_p[0] + 1.0f);

    const int wave = tid >> 6;          // 0..3
    const int lane = tid & 63;
    const int R0 = blockIdx.x * 32;     // grid 3125 exact
    const int rbase = R0 + wave * 8;

    // lanes 0..8 hold row_ptr bounds for this wave's 8 rows
    const int rpidx = rbase + ((lane < 9) ? lane : 8);
    const int rp_l = row_ptr[rpidx];

    for (int i = 0; i < 8; ++i) {
        const int r = rbase + i;
        const int s = __builtin_amdgcn_readlane(rp_l, i);
        const int t = __builtin_amdgcn_readlane(rp_l, i + 1);

        const float h0v = ntl(&H0[(size_t)r * D + lane]);  // hoisted, overlaps loop

        float a0 = 0.f, a1 = 0.f, a2 = 0.f, a3 = 0.f;
        unsigned p_l = 0;
        if (s < t) {
            int ei = s + (lane & 15);
            if (ei > t - 1) ei = t - 1;
            p_l = ntl(pack + ei);
        }
        int e = s;
        while (e < t) {
            const int ebase = e;
            const unsigned p_cur = p_l;
            e += 16;
            if (e < t) {                       // prefetch next group early
                int ei = e + (lane & 15);
                if (ei > t - 1) ei = t - 1;
                p_l = ntl(pack + ei);
            }
            #pragma unroll
            for (int k = 0; k < 16; ++k) {
                const unsigned p = (unsigned)__builtin_amdgcn_readlane((int)p_cur, k);
                const unsigned vbits = (ebase + k < t) ? (p & 0x7FFFu) : 0u;
                const float v = h_from_bits(vbits);
                const unsigned short hb = Hh[(size_t)(p >> 15) * D + lane];  // cached
                __half hh; __builtin_memcpy(&hh, &hb, 2);
                const float hf = __half2float(hh);
                if ((k & 3) == 0) a0 = fmaf(v, hf, a0);
                else if ((k & 3) == 1) a1 = fmaf(v, hf, a1);
                else if ((k & 3) == 2) a2 = fmaf(v, hf, a2);
                else a3 = fmaf(v, hf, a3);
            }
        }
        const float acc = (a0 + a1) + (a2 + a3);
        const float sup = (1.0f - alpha) * acc + alpha * h0v;
        supT[lane][wave * 8 + i] = sup;
    }
    __syncthreads();

    // 32x64 mini-GEMM: 2x4 register tile per thread, fp16 B operand
    const int ty = tid >> 4;     // 0..15 -> rows 2ty, 2ty+1
    const int tx = tid & 15;     // 0..15 -> cols 4tx..4tx+3
    float acc[2][4] = {{0.f}};

    #pragma unroll 8
    for (int k = 0; k < D; ++k) {
        const float2 A = *reinterpret_cast<const float2*>(&supT[k][2 * ty]);
        const __half2 b01 = *reinterpret_cast<const __half2*>(&Wlh[k][4 * tx]);
        const __half2 b23 = *reinterpret_cast<const __half2*>(&Wlh[k][4 * tx + 2]);
        const float2 B01 = __half22float2(b01);
        const float2 B23 = __half22float2(b23);
        acc[0][0] = fmaf(A.x, B01.x, acc[0][0]); acc[0][1] = fmaf(A.x, B01.y, acc[0][1]);
        acc[0][2] = fmaf(A.x, B23.x, acc[0][2]); acc[0][3] = fmaf(A.x, B23.y, acc[0][3]);
        acc[1][0] = fmaf(A.y, B01.x, acc[1][0]); acc[1][1] = fmaf(A.y, B01.y, acc[1][1]);
        acc[1][2] = fmaf(A.y, B23.x, acc[1][2]); acc[1][3] = fmaf(A.y, B23.y, acc[1][3]);
    }

    #pragma unroll
    for (int i = 0; i < 2; ++i) {
        const int r = R0 + 2 * ty + i;
        f32x4 o;
        o.x = (1.0f - beta) * supT[4 * tx + 0][2 * ty + i] + beta * acc[i][0];
        o.y = (1.0f - beta) * supT[4 * tx + 1][2 * ty + i] + beta * acc[i][1];
        o.z = (1.0f - beta) * supT[4 * tx + 2][2 * ty + i] + beta * acc[i][2];
        o.w = (1.0f - beta) * supT[4 * tx + 3][2 * ty + i] + beta * acc[i][3];
        __builtin_nontemporal_store(o,
            reinterpret_cast<f32x4*>(&out[(size_t)r * D + 4 * tx]));
    }
}

// ===========================================================================
// Tier A fallback build (round-6): hist + scan + atomic-cursor scatter
// ===========================================================================
__global__ void hist_kernel(const int* __restrict__ row, int* __restrict__ counts) {
    int e = blockIdx.x * blockDim.x + threadIdx.x;
    if (e >= N_EDGES) return;
    atomicAdd(&counts[row[e]], 1);
}

__global__ void __launch_bounds__(256)
scan1_kernel(const int* __restrict__ counts, int* __restrict__ row_ptr,
             int* __restrict__ chunkTotals) {
    __shared__ int s[256];
    const int t = threadIdx.x;
    const int base = blockIdx.x * CHUNK + t * 4;
    int c0 = (base + 0 < N_NODES) ? counts[base + 0] : 0;
    int c1 = (base + 1 < N_NODES) ? counts[base + 1] : 0;
    int c2 = (base + 2 < N_NODES) ? counts[base + 2] : 0;
    int c3 = (base + 3 < N_NODES) ? counts[base + 3] : 0;
    const int sum = c0 + c1 + c2 + c3;
    s[t] = sum;
    __syncthreads();
    for (int off = 1; off < 256; off <<= 1) {
        int u = (t >= off) ? s[t - off] : 0;
        __syncthreads();
        s[t] += u;
        __syncthreads();
    }
    const int excl = s[t] - sum;
    if (base + 0 < N_NODES) row_ptr[base + 0] = excl;
    if (base + 1 < N_NODES) row_ptr[base + 1] = excl + c0;
    if (base + 2 < N_NODES) row_ptr[base + 2] = excl + c0 + c1;
    if (base + 3 < N_NODES) row_ptr[base + 3] = excl + c0 + c1 + c2;
    if (t == 255) chunkTotals[blockIdx.x] = s[255];
}

__global__ void __launch_bounds__(256)
scan2_kernel(int* __restrict__ row_ptr, int* __restrict__ cursor,
             const int* __restrict__ chunkTotals) {
    int offset = 0;
    for (int i = 0; i < (int)blockIdx.x; ++i) offset += chunkTotals[i];
    const int idx = blockIdx.x * CHUNK + threadIdx.x * 4;
    #pragma unroll
    for (int j = 0; j < 4; ++j) {
        const int k = idx + j;
        if (k < N_NODES) {
            const int v = row_ptr[k] + offset;
            row_ptr[k] = v;
            cursor[k]  = v;
        }
    }
    if (blockIdx.x == 0 && threadIdx.x == 0) row_ptr[N_NODES] = N_EDGES;
}

__global__ void scatter_pack_kernel(const int* __restrict__ row, const int* __restrict__ col,
                                    const float* __restrict__ vals,
                                    int* __restrict__ cursor,
                                    unsigned* __restrict__ pack) {
    int e = blockIdx.x * blockDim.x + threadIdx.x;
    if (e >= N_EDGES) return;
    const int pos = atomicAdd(&cursor[row[e]], 1);
    __half hv = __float2half_rn(vals[e]);
    unsigned short hb;
    __builtin_memcpy(&hb, &hv, 2);
    pack[pos] = ((unsigned)col[e] << 15) | (hb & 0x7FFFu);
}

// round-6-compatible gather (64 rows/block) for the fallback tier
__global__ void __launch_bounds__(256)
gather_gemm64_kernel(const int* __restrict__ row_ptr,
                     const unsigned* __restrict__ pack,
                     const unsigned short* __restrict__ Hh,
                     const float* __restrict__ H0,
                     const float* __restrict__ W,
                     const float* __restrict__ lamda_p, const float* __restrict__ alpha_p,
                     const int* __restrict__ l_p,
                     float* __restrict__ out) {
    __shared__ float supT[D][68];
    __shared__ float Wl[D][D];

    const int tid = threadIdx.x;
    for (int i = tid; i < D * D; i += 256) ((float*)Wl)[i] = W[i];

    const float alpha = alpha_p[0];
    const float beta  = logf(lamda_p[0] / (float)l_p[0] + 1.0f);

    const int wave = tid >> 6;
    const int lane = tid & 63;
    const int R0 = blockIdx.x * 64;
    const int rbase = R0 + wave * 16;

    int rpidx = rbase + ((lane < 17) ? lane : 16);
    if (rpidx > N_NODES) rpidx = N_NODES;
    const int rp_l = row_ptr[rpidx];

    for (int i = 0; i < 16; ++i) {
        const int r = rbase + i;
        if (r >= N_NODES) break;
        const int s = __builtin_amdgcn_readlane(rp_l, i);
        const int t = __builtin_amdgcn_readlane(rp_l, i + 1);
        const float h0v = ntl(&H0[(size_t)r * D + lane]);
        float a0 = 0.f, a1 = 0.f, a2 = 0.f, a3 = 0.f;
        unsigned p_l = 0;
        if (s < t) {
            int ei = s + (lane & 15);
            if (ei > t - 1) ei = t - 1;
            p_l = ntl(pack + ei);
        }
        int e = s;
        while (e < t) {
            const int ebase = e;
            const unsigned p_cur = p_l;
            e += 16;
            if (e < t) {
                int ei = e + (lane & 15);
                if (ei > t - 1) ei = t - 1;
                p_l = ntl(pack + ei);
            }
            #pragma unroll
            for (int k = 0; k < 16; ++k) {
                const unsigned p = (unsigned)__builtin_amdgcn_readlane((int)p_cur, k);
                const unsigned vbits = (ebase + k < t) ? (p & 0x7FFFu) : 0u;
                const float v = h_from_bits(vbits);
                const unsigned short hb = Hh[(size_t)(p >> 15) * D + lane];
                __half hh; __builtin_memcpy(&hh, &hb, 2);
                const float hf = __half2float(hh);
                if ((k & 3) == 0) a0 = fmaf(v, hf, a0);
                else if ((k & 3) == 1) a1 = fmaf(v, hf, a1);
                else if ((k & 3) == 2) a2 = fmaf(v, hf, a2);
                else a3 = fmaf(v, hf, a3);
            }
        }
        const float acc = (a0 + a1) + (a2 + a3);
        const float sup = (1.0f - alpha) * acc + alpha * h0v;
        supT[lane][wave * 16 + i] = sup;
    }
    __syncthreads();

    const int ty = tid >> 4;
    const int tx = tid & 15;
    float acc[4][4] = {{0.f}};
    #pragma unroll 8
    for (int k = 0; k < D; ++k) {
        const float4 A = *reinterpret_cast<const float4*>(&supT[k][4 * ty]);
        const float4 B = *reinterpret_cast<const float4*>(&Wl[k][4 * tx]);
        acc[0][0] = fmaf(A.x, B.x, acc[0][0]); acc[0][1] = fmaf(A.x, B.y, acc[0][1]);
        acc[0][2] = fmaf(A.x, B.z, acc[0][2]); acc[0][3] = fmaf(A.x, B.w, acc[0][3]);
        acc[1][0] = fmaf(A.y, B.x, acc[1][0]); acc[1][1] = fmaf(A.y, B.y, acc[1][1]);
        acc[1][2] = fmaf(A.y, B.z, acc[1][2]); acc[1][3] = fmaf(A.y, B.w, acc[1][3]);
        acc[2][0] = fmaf(A.z, B.x, acc[2][0]); acc[2][1] = fmaf(A.z, B.y, acc[2][1]);
        acc[2][2] = fmaf(A.z, B.z, acc[2][2]); acc[2][3] = fmaf(A.z, B.w, acc[2][3]);
        acc[3][0] = fmaf(A.w, B.x, acc[3][0]); acc[3][1] = fmaf(A.w, B.y, acc[3][1]);
        acc[3][2] = fmaf(A.w, B.z, acc[3][2]); acc[3][3] = fmaf(A.w, B.w, acc[3][3]);
    }
    #pragma unroll
    for (int i = 0; i < 4; ++i) {
        const int r = R0 + 4 * ty + i;
        if (r < N_NODES) {
            f32x4 o;
            o.x = (1.0f - beta) * supT[4 * tx + 0][4 * ty + i] + beta * acc[i][0];
            o.y = (1.0f - beta) * supT[4 * tx + 1][4 * ty + i] + beta * acc[i][1];
            o.z = (1.0f - beta) * supT[4 * tx + 2][4 * ty + i] + beta * acc[i][2];
            o.w = (1.0f - beta) * supT[4 * tx + 3][4 * ty + i] + beta * acc[i][3];
            __builtin_nontemporal_store(o,
                reinterpret_cast<f32x4*>(&out[(size_t)r * D + 4 * tx]));
        }
    }
}

// ===========================================================================
// Tier C fallback: f32 atomic scatter + separate epilogue
// ===========================================================================
__global__ void spmm_atomic_kernel(const int* __restrict__ row,
                                   const int* __restrict__ col,
                                   const float* __restrict__ vals,
                                   const float* __restrict__ H,
                                   float* __restrict__ AH) {
    const long long total = (long long)N_EDGES * 16;
    long long idx = (long long)blockIdx.x * blockDim.x + threadIdx.x;
    if (idx >= total) return;
    const int e   = (int)(idx >> 4);
    const int sub = (int)(idx & 15);
    const int r   = row[e];
    const int c   = col[e];
    const float v = vals[e];
    const float4 h = *reinterpret_cast<const float4*>(&H[(long long)c * D + sub * 4]);
    float* dst = &AH[(long long)r * D + sub * 4];
    atomicAdd(dst + 0, v * h.x);
    atomicAdd(dst + 1, v * h.y);
    atomicAdd(dst + 2, v * h.z);
    atomicAdd(dst + 3, v * h.w);
}

__global__ void __launch_bounds__(256)
gcnii_epilogue_kernel(float* __restrict__ AH_out,
                      const float* __restrict__ H0,
                      const float* __restrict__ W,
                      const float* __restrict__ lamda_p,
                      const float* __restrict__ alpha_p,
                      const int* __restrict__ l_p) {
    __shared__ float Wlds[D * D];
    for (int i = threadIdx.x; i < D * D; i += 256) Wlds[i] = W[i];
    __syncthreads();
    const float alpha = alpha_p[0];
    const float beta  = logf(lamda_p[0] / (float)l_p[0] + 1.0f);
    const int wave = threadIdx.x >> 6;
    const int lane = threadIdx.x & 63;
    const int r = blockIdx.x * 4 + wave;
    if (r >= N_NODES) return;
    const long long base = (long long)r * D;
    const float sup = (1.0f - alpha) * AH_out[base + lane] + alpha * H0[base + lane];
    float acc = 0.0f;
    #pragma unroll
    for (int k = 0; k < D; ++k)
        acc = fmaf(__shfl(sup, k, 64), Wlds[k * D + lane], acc);
    AH_out[base + lane] = (1.0f - beta) * sup + beta * acc;
}

// ===========================================================================
extern "C" void kernel_launch(void* const* d_in, const int* in_sizes, int n_in,
                              void* d_out, int out_size, void* d_ws, size_t ws_size,
                              hipStream_t stream) {
    const int*   row   = (const int*)  d_in[0];
    const int*   col   = (const int*)  d_in[1];
    const float* vals  = (const float*)d_in[2];
    const float* H     = (const float*)d_in[3];
    const float* H0    = (const float*)d_in[4];
    const float* W     = (const float*)d_in[5];
    const float* lamda = (const float*)d_in[6];
    const float* alpha = (const float*)d_in[7];
    const int*   l     = (const int*)  d_in[8];
    float* out = (float*)d_out;

    // Tier A2 layout (4B words):
    //   binCounts : [0, 512)
    //   binBase   : [512, 1024)      (401 used)
    //   binCursor : [1024, 1536)
    //   row_ptr   : [1536, 101568)   (100001 used)
    //   pack4     : [101568, 1701568)
    //   tmp2(u16) : [1701568, 2501568)
    //   tmp4      : [2501568, 4101568)
    //   Hh (fp16) : [4101568, 7301568)
    const size_t neededA2 = (size_t)7301568 * 4;   // 29.2 MB
    const size_t neededA  = (size_t)5000256 * 4;   // 20.0 MB (round-6 path)

    if (ws_size >= neededA2) {
        int*            binCounts = (int*)d_ws;
        int*            binBase   = binCounts + 512;
        int*            binCursor = binCounts + 1024;
        int*            row_ptr   = binCounts + 1536;
        unsigned*       pack      = (unsigned*)(binCounts + 101568);
        unsigned short* tmp2      = (unsigned short*)(binCounts + 1701568);
        unsigned*       tmp4      = (unsigned*)(binCounts + 2501568);
        unsigned short* Hh        = (unsigned short*)(binCounts + 4101568);

        h2half_kernel<<<(N_NODES * D / 4 + 255) / 256, 256, 0, stream>>>(H, Hh);
        hipMemsetAsync(binCounts, 0, NBIN * sizeof(int), stream);
        bin_hist_kernel<<<608, 256, 0, stream>>>(row, binCounts);
        bin_scan_kernel<<<1, 512, 0, stream>>>(binCounts, binBase, binCursor);
        multisplit_kernel<<<(N_EDGES + MS_TILE - 1) / MS_TILE, 256, 0, stream>>>(
            row, col, vals, binCursor, tmp4, tmp2);
        bin_sort_kernel<<<NBIN, 512, 0, stream>>>(binBase, tmp4, tmp2, row_ptr, pack);
        gather_gemm_kernel<<<N_NODES / 32, 256, 0, stream>>>(
            row_ptr, pack, Hh, H0, W, lamda, alpha, l, out);
    } else if (ws_size >= neededA) {
        // round-6 tier A
        int*            counts  = (int*)d_ws;
        int*            row_ptr = counts + 100000;
        int*            totals  = counts + 200064;
        unsigned*       pack    = (unsigned*)(counts + 200192);
        unsigned short* Hh      = (unsigned short*)(counts + 1800256);

        h2half_kernel<<<(N_NODES * D / 4 + 255) / 256, 256, 0, stream>>>(H, Hh);
        hipMemsetAsync(counts, 0, (size_t)N_NODES * sizeof(int), stream);
        hist_kernel<<<(N_EDGES + 255) / 256, 256, 0, stream>>>(row, counts);
        scan1_kernel<<<NCHUNK, 256, 0, stream>>>(counts, row_ptr, totals);
        scan2_kernel<<<NCHUNK, 256, 0, stream>>>(row_ptr, counts, totals);
        scatter_pack_kernel<<<(N_EDGES + 255) / 256, 256, 0, stream>>>(row, col, vals,
                                                                       counts, pack);
        gather_gemm64_kernel<<<(N_NODES + 63) / 64, 256, 0, stream>>>(
            row_ptr, pack, Hh, H0, W, lamda, alpha, l, out);
    } else {
        hipMemsetAsync(out, 0, (size_t)out_size * sizeof(float), stream);
        const long long total = (long long)N_EDGES * 16;
        spmm_atomic_kernel<<<(int)((total + 255) / 256), 256, 0, stream>>>(row, col, vals, H, out);
        gcnii_epilogue_kernel<<<(N_NODES + 3) / 4, 256, 0, stream>>>(out, H0, W,
                                                                     lamda, alpha, l);
    }
}

// Round 13
// 120.722 us; speedup vs baseline: 1.1333x; 1.1333x over previous
//
#include <hip/hip_runtime.h>
#include <hip/hip_bf16.h>
#include <hip/hip_fp16.h>

#define N_NODES 100000
#define N_EDGES 1600000
#define D 64
#define CHUNK 1024
#define NCHUNK ((N_NODES + CHUNK - 1) / CHUNK)   // 98

// ---- tier A2 multisplit parameters (round-11 proven) ----
#define NBIN 400          // bins of 250 rows
#define RPB  250          // rows per bin
#define MS_TILE 4096      // edges per multisplit block (391 blocks)
#define MS_CAP  24        // LDS slots per bin per tile (mean 10.2)
#define SCAP 4352         // bin staging cap in bin_sort (mean 4000)

typedef float f32x4 __attribute__((ext_vector_type(4)));

template <typename T>
__device__ __forceinline__ T ntl(const T* p) { return __builtin_nontemporal_load(p); }

// ===========================================================================
// Tier A2 build — round-11 configuration (measured best)
// ===========================================================================

// --- H -> fp16 (plain loads, 6250 blocks) ----------------------------------
__global__ void __launch_bounds__(256)
h2half_kernel(const float* __restrict__ H, unsigned short* __restrict__ Hh) {
    const int tid = blockIdx.x * blockDim.x + threadIdx.x;
    const int total = N_NODES * D / 4;
    if (tid >= total) return;
    const float4 f = reinterpret_cast<const float4*>(H)[tid];
    __half2 h01 = __floats2half2_rn(f.x, f.y);
    __half2 h23 = __floats2half2_rn(f.z, f.w);
    uint2 u;
    __builtin_memcpy(&u.x, &h01, 4);
    __builtin_memcpy(&u.y, &h23, 4);
    reinterpret_cast<uint2*>(Hh)[tid] = u;
}

// --- A2.1: 400-bin histogram (LDS-staged) -----------------------------------
__global__ void __launch_bounds__(256)
bin_hist_kernel(const int* __restrict__ row, int* __restrict__ binCounts) {
    __shared__ int h[NBIN];
    for (int i = threadIdx.x; i < NBIN; i += 256) h[i] = 0;
    __syncthreads();
    for (int e = blockIdx.x * blockDim.x + threadIdx.x; e < N_EDGES;
         e += gridDim.x * blockDim.x)
        atomicAdd(&h[row[e] / RPB], 1);
    __syncthreads();
    for (int i = threadIdx.x; i < NBIN; i += 256)
        atomicAdd(&binCounts[i], h[i]);
}

// --- A2.2: scan 400 bin counts -> binBase[0..NBIN], binCursor ---------------
__global__ void __launch_bounds__(512)
bin_scan_kernel(const int* __restrict__ binCounts,
                int* __restrict__ binBase, int* __restrict__ binCursor) {
    __shared__ int s[512];
    const int tid = threadIdx.x;
    const int cnt = (tid < NBIN) ? binCounts[tid] : 0;
    s[tid] = cnt;
    __syncthreads();
    for (int off = 1; off < 512; off <<= 1) {
        int t = (tid >= off) ? s[tid - off] : 0;
        __syncthreads();
        s[tid] += t;
        __syncthreads();
    }
    const int excl = s[tid] - cnt;
    if (tid < NBIN) {
        binBase[tid]   = excl;
        binCursor[tid] = excl;
        if (tid == NBIN - 1) binBase[NBIN] = s[tid];   // == N_EDGES
    }
}

// --- A2.3: multisplit — partition edges into 400 bins, LDS-buffered ---------
// 391 blocks x 4096 edges (round-11 proven parameters)
__global__ void __launch_bounds__(256)
multisplit_kernel(const int* __restrict__ row, const int* __restrict__ col,
                  const float* __restrict__ vals,
                  int* __restrict__ binCursor,
                  unsigned* __restrict__ tmp4, unsigned short* __restrict__ tmp2) {
    __shared__ unsigned       spay[NBIN][MS_CAP];   // 38.4 KB
    __shared__ unsigned short srow[NBIN][MS_CAP];   // 19.2 KB
    __shared__ int bcnt[NBIN];                      // 1.6 KB
    __shared__ int gb[NBIN];                        // 1.6 KB

    const int tid = threadIdx.x;
    for (int i = tid; i < NBIN; i += 256) bcnt[i] = 0;
    __syncthreads();

    const int base = blockIdx.x * MS_TILE;
    const int eEnd = min(base + MS_TILE, N_EDGES);

    #pragma unroll
    for (int j = 0; j < MS_TILE / 256; ++j) {
        const int e = base + j * 256 + tid;
        if (e < eEnd) {
            const int r = row[e];
            const int c = col[e];
            __half hv = __float2half_rn(vals[e]);       // vals >= 0 -> sign 0
            unsigned short hb;
            __builtin_memcpy(&hb, &hv, 2);
            const unsigned pk = ((unsigned)c << 15) | (hb & 0x7FFFu);
            const int bin = r / RPB;
            const unsigned short rl = (unsigned short)(r - bin * RPB);
            const int p = atomicAdd(&bcnt[bin], 1);
            if (p < MS_CAP) {
                spay[bin][p] = pk;
                srow[bin][p] = rl;
            } else {                                    // rare spill
                const int g = atomicAdd(&binCursor[bin], 1);
                tmp4[g] = pk;
                tmp2[g] = rl;
            }
        }
    }
    __syncthreads();

    for (int i = tid; i < NBIN; i += 256) {
        const int c = min(bcnt[i], MS_CAP);
        gb[i] = atomicAdd(&binCursor[i], c);
    }
    __syncthreads();

    for (int i = tid; i < NBIN * MS_CAP; i += 256) {
        const int bin  = i / MS_CAP;
        const int slot = i - bin * MS_CAP;
        if (slot < min(bcnt[bin], MS_CAP)) {
            const int g = gb[bin] + slot;
            tmp4[g] = spay[bin][slot];
            tmp2[g] = srow[bin][slot];
        }
    }
}

// --- A2.4: per-bin LDS counting sort -> row_ptr + sorted pack ---------------
__global__ void __launch_bounds__(512)
bin_sort_kernel(const int* __restrict__ binBase,
                const unsigned* __restrict__ tmp4, const unsigned short* __restrict__ tmp2,
                int* __restrict__ row_ptr, unsigned* __restrict__ pack) {
    __shared__ unsigned       pay[SCAP];     // 17.4 KB
    __shared__ unsigned short rl[SCAP];      // 8.7 KB
    __shared__ int rcnt[512];
    __shared__ int rex[512];

    const int tid = threadIdx.x;
    const int b    = blockIdx.x;
    const int base = binBase[b];
    const int nb   = binBase[b + 1] - base;
    const int row0 = b * RPB;

    rcnt[tid] = 0;
    __syncthreads();

    // phase A: stage + histogram
    for (int i = tid; i < nb; i += 512) {
        const unsigned       p = tmp4[base + i];
        const unsigned short r = tmp2[base + i];
        if (i < SCAP) { pay[i] = p; rl[i] = r; }
        atomicAdd(&rcnt[r], 1);
    }
    __syncthreads();

    // phase B: exclusive scan of 250 counts
    const int cnt = rcnt[tid];
    rex[tid] = cnt;
    __syncthreads();
    for (int off = 1; off < 512; off <<= 1) {
        int t = (tid >= off) ? rex[tid - off] : 0;
        __syncthreads();
        rex[tid] += t;
        __syncthreads();
    }
    const int excl = rex[tid] - cnt;
    if (tid < RPB) row_ptr[row0 + tid] = base + excl;
    if (b == NBIN - 1 && tid == 0) row_ptr[N_NODES] = N_EDGES;
    __syncthreads();
    rcnt[tid] = excl;          // reuse as within-bin cursor
    __syncthreads();

    // phase C: scatter into sorted order (one L2 -> write-combined)
    for (int i = tid; i < nb; i += 512) {
        unsigned p; unsigned short r;
        if (i < SCAP) { p = pay[i]; r = rl[i]; }
        else          { p = tmp4[base + i]; r = tmp2[base + i]; }
        const int d = atomicAdd(&rcnt[r], 1);
        pack[base + d] = p;
    }
}

// ===========================================================================
// Fused gather-SPMM + GCNII epilogue — round-12 version (measured 65 us)
// 32 rows/block, fp16 W in LDS; 17.2 KB -> 8 blocks/CU
// ===========================================================================
__device__ inline float h_from_bits(unsigned bits) {
    unsigned short us = (unsigned short)bits;
    __half h;
    __builtin_memcpy(&h, &us, 2);
    return __half2float(h);
}

__global__ void __launch_bounds__(256)
gather_gemm_kernel(const int* __restrict__ row_ptr,
                   const unsigned* __restrict__ pack,
                   const unsigned short* __restrict__ Hh,
                   const float* __restrict__ H0,
                   const float* __restrict__ W,
                   const float* __restrict__ lamda_p, const float* __restrict__ alpha_p,
                   const int* __restrict__ l_p,
                   float* __restrict__ out) {
    __shared__ float  supT[D][36];   // 9.2 KB: 32 rows + 4 pad
    __shared__ __half Wlh[D][D];     // 8 KB

    const int tid = threadIdx.x;
    for (int i = tid; i < D * D; i += 256)
        ((__half*)Wlh)[i] = __float2half_rn(W[i]);

    const float alpha = alpha_p[0];
    const float beta  = logf(lamda_p[0] / (float)l_p[0] + 1.0f);

    const int wave = tid >> 6;          // 0..3
    const int lane = tid & 63;
    const int R0 = blockIdx.x * 32;     // grid 3125 exact
    const int rbase = R0 + wave * 8;

    // lanes 0..8 hold row_ptr bounds for this wave's 8 rows
    const int rpidx = rbase + ((lane < 9) ? lane : 8);
    const int rp_l = row_ptr[rpidx];

    for (int i = 0; i < 8; ++i) {
        const int r = rbase + i;
        const int s = __builtin_amdgcn_readlane(rp_l, i);
        const int t = __builtin_amdgcn_readlane(rp_l, i + 1);

        const float h0v = ntl(&H0[(size_t)r * D + lane]);  // hoisted, overlaps loop

        float a0 = 0.f, a1 = 0.f, a2 = 0.f, a3 = 0.f;
        unsigned p_l = 0;
        if (s < t) {
            int ei = s + (lane & 15);
            if (ei > t - 1) ei = t - 1;
            p_l = ntl(pack + ei);
        }
        int e = s;
        while (e < t) {
            const int ebase = e;
            const unsigned p_cur = p_l;
            e += 16;
            if (e < t) {                       // prefetch next group early
                int ei = e + (lane & 15);
                if (ei > t - 1) ei = t - 1;
                p_l = ntl(pack + ei);
            }
            #pragma unroll
            for (int k = 0; k < 16; ++k) {
                const unsigned p = (unsigned)__builtin_amdgcn_readlane((int)p_cur, k);
                const unsigned vbits = (ebase + k < t) ? (p & 0x7FFFu) : 0u;
                const float v = h_from_bits(vbits);
                const unsigned short hb = Hh[(size_t)(p >> 15) * D + lane];  // cached
                __half hh; __builtin_memcpy(&hh, &hb, 2);
                const float hf = __half2float(hh);
                if ((k & 3) == 0) a0 = fmaf(v, hf, a0);
                else if ((k & 3) == 1) a1 = fmaf(v, hf, a1);
                else if ((k & 3) == 2) a2 = fmaf(v, hf, a2);
                else a3 = fmaf(v, hf, a3);
            }
        }
        const float acc = (a0 + a1) + (a2 + a3);
        const float sup = (1.0f - alpha) * acc + alpha * h0v;
        supT[lane][wave * 8 + i] = sup;
    }
    __syncthreads();

    // 32x64 mini-GEMM: 2x4 register tile per thread, fp16 B operand
    const int ty = tid >> 4;     // 0..15 -> rows 2ty, 2ty+1
    const int tx = tid & 15;     // 0..15 -> cols 4tx..4tx+3
    float acc[2][4] = {{0.f}};

    #pragma unroll 8
    for (int k = 0; k < D; ++k) {
        const float2 A = *reinterpret_cast<const float2*>(&supT[k][2 * ty]);
        const __half2 b01 = *reinterpret_cast<const __half2*>(&Wlh[k][4 * tx]);
        const __half2 b23 = *reinterpret_cast<const __half2*>(&Wlh[k][4 * tx + 2]);
        const float2 B01 = __half22float2(b01);
        const float2 B23 = __half22float2(b23);
        acc[0][0] = fmaf(A.x, B01.x, acc[0][0]); acc[0][1] = fmaf(A.x, B01.y, acc[0][1]);
        acc[0][2] = fmaf(A.x, B23.x, acc[0][2]); acc[0][3] = fmaf(A.x, B23.y, acc[0][3]);
        acc[1][0] = fmaf(A.y, B01.x, acc[1][0]); acc[1][1] = fmaf(A.y, B01.y, acc[1][1]);
        acc[1][2] = fmaf(A.y, B23.x, acc[1][2]); acc[1][3] = fmaf(A.y, B23.y, acc[1][3]);
    }

    #pragma unroll
    for (int i = 0; i < 2; ++i) {
        const int r = R0 + 2 * ty + i;
        f32x4 o;
        o.x = (1.0f - beta) * supT[4 * tx + 0][2 * ty + i] + beta * acc[i][0];
        o.y = (1.0f - beta) * supT[4 * tx + 1][2 * ty + i] + beta * acc[i][1];
        o.z = (1.0f - beta) * supT[4 * tx + 2][2 * ty + i] + beta * acc[i][2];
        o.w = (1.0f - beta) * supT[4 * tx + 3][2 * ty + i] + beta * acc[i][3];
        __builtin_nontemporal_store(o,
            reinterpret_cast<f32x4*>(&out[(size_t)r * D + 4 * tx]));
    }
}

// ===========================================================================
// Tier A fallback build (round-6): hist + scan + atomic-cursor scatter
// ===========================================================================
__global__ void hist_kernel(const int* __restrict__ row, int* __restrict__ counts) {
    int e = blockIdx.x * blockDim.x + threadIdx.x;
    if (e >= N_EDGES) return;
    atomicAdd(&counts[row[e]], 1);
}

__global__ void __launch_bounds__(256)
scan1_kernel(const int* __restrict__ counts, int* __restrict__ row_ptr,
             int* __restrict__ chunkTotals) {
    __shared__ int s[256];
    const int t = threadIdx.x;
    const int base = blockIdx.x * CHUNK + t * 4;
    int c0 = (base + 0 < N_NODES) ? counts[base + 0] : 0;
    int c1 = (base + 1 < N_NODES) ? counts[base + 1] : 0;
    int c2 = (base + 2 < N_NODES) ? counts[base + 2] : 0;
    int c3 = (base + 3 < N_NODES) ? counts[base + 3] : 0;
    const int sum = c0 + c1 + c2 + c3;
    s[t] = sum;
    __syncthreads();
    for (int off = 1; off < 256; off <<= 1) {
        int u = (t >= off) ? s[t - off] : 0;
        __syncthreads();
        s[t] += u;
        __syncthreads();
    }
    const int excl = s[t] - sum;
    if (base + 0 < N_NODES) row_ptr[base + 0] = excl;
    if (base + 1 < N_NODES) row_ptr[base + 1] = excl + c0;
    if (base + 2 < N_NODES) row_ptr[base + 2] = excl + c0 + c1;
    if (base + 3 < N_NODES) row_ptr[base + 3] = excl + c0 + c1 + c2;
    if (t == 255) chunkTotals[blockIdx.x] = s[255];
}

__global__ void __launch_bounds__(256)
scan2_kernel(int* __restrict__ row_ptr, int* __restrict__ cursor,
             const int* __restrict__ chunkTotals) {
    int offset = 0;
    for (int i = 0; i < (int)blockIdx.x; ++i) offset += chunkTotals[i];
    const int idx = blockIdx.x * CHUNK + threadIdx.x * 4;
    #pragma unroll
    for (int j = 0; j < 4; ++j) {
        const int k = idx + j;
        if (k < N_NODES) {
            const int v = row_ptr[k] + offset;
            row_ptr[k] = v;
            cursor[k]  = v;
        }
    }
    if (blockIdx.x == 0 && threadIdx.x == 0) row_ptr[N_NODES] = N_EDGES;
}

__global__ void scatter_pack_kernel(const int* __restrict__ row, const int* __restrict__ col,
                                    const float* __restrict__ vals,
                                    int* __restrict__ cursor,
                                    unsigned* __restrict__ pack) {
    int e = blockIdx.x * blockDim.x + threadIdx.x;
    if (e >= N_EDGES) return;
    const int pos = atomicAdd(&cursor[row[e]], 1);
    __half hv = __float2half_rn(vals[e]);
    unsigned short hb;
    __builtin_memcpy(&hb, &hv, 2);
    pack[pos] = ((unsigned)col[e] << 15) | (hb & 0x7FFFu);
}

// round-6-compatible gather (64 rows/block) for the fallback tier
__global__ void __launch_bounds__(256)
gather_gemm64_kernel(const int* __restrict__ row_ptr,
                     const unsigned* __restrict__ pack,
                     const unsigned short* __restrict__ Hh,
                     const float* __restrict__ H0,
                     const float* __restrict__ W,
                     const float* __restrict__ lamda_p, const float* __restrict__ alpha_p,
                     const int* __restrict__ l_p,
                     float* __restrict__ out) {
    __shared__ float supT[D][68];
    __shared__ float Wl[D][D];

    const int tid = threadIdx.x;
    for (int i = tid; i < D * D; i += 256) ((float*)Wl)[i] = W[i];

    const float alpha = alpha_p[0];
    const float beta  = logf(lamda_p[0] / (float)l_p[0] + 1.0f);

    const int wave = tid >> 6;
    const int lane = tid & 63;
    const int R0 = blockIdx.x * 64;
    const int rbase = R0 + wave * 16;

    int rpidx = rbase + ((lane < 17) ? lane : 16);
    if (rpidx > N_NODES) rpidx = N_NODES;
    const int rp_l = row_ptr[rpidx];

    for (int i = 0; i < 16; ++i) {
        const int r = rbase + i;
        if (r >= N_NODES) break;
        const int s = __builtin_amdgcn_readlane(rp_l, i);
        const int t = __builtin_amdgcn_readlane(rp_l, i + 1);
        const float h0v = ntl(&H0[(size_t)r * D + lane]);
        float a0 = 0.f, a1 = 0.f, a2 = 0.f, a3 = 0.f;
        unsigned p_l = 0;
        if (s < t) {
            int ei = s + (lane & 15);
            if (ei > t - 1) ei = t - 1;
            p_l = ntl(pack + ei);
        }
        int e = s;
        while (e < t) {
            const int ebase = e;
            const unsigned p_cur = p_l;
            e += 16;
            if (e < t) {
                int ei = e + (lane & 15);
                if (ei > t - 1) ei = t - 1;
                p_l = ntl(pack + ei);
            }
            #pragma unroll
            for (int k = 0; k < 16; ++k) {
                const unsigned p = (unsigned)__builtin_amdgcn_readlane((int)p_cur, k);
                const unsigned vbits = (ebase + k < t) ? (p & 0x7FFFu) : 0u;
                const float v = h_from_bits(vbits);
                const unsigned short hb = Hh[(size_t)(p >> 15) * D + lane];
                __half hh; __builtin_memcpy(&hh, &hb, 2);
                const float hf = __half2float(hh);
                if ((k & 3) == 0) a0 = fmaf(v, hf, a0);
                else if ((k & 3) == 1) a1 = fmaf(v, hf, a1);
                else if ((k & 3) == 2) a2 = fmaf(v, hf, a2);
                else a3 = fmaf(v, hf, a3);
            }
        }
        const float acc = (a0 + a1) + (a2 + a3);
        const float sup = (1.0f - alpha) * acc + alpha * h0v;
        supT[lane][wave * 16 + i] = sup;
    }
    __syncthreads();

    const int ty = tid >> 4;
    const int tx = tid & 15;
    float acc[4][4] = {{0.f}};
    #pragma unroll 8
    for (int k = 0; k < D; ++k) {
        const float4 A = *reinterpret_cast<const float4*>(&supT[k][4 * ty]);
        const float4 B = *reinterpret_cast<const float4*>(&Wl[k][4 * tx]);
        acc[0][0] = fmaf(A.x, B.x, acc[0][0]); acc[0][1] = fmaf(A.x, B.y, acc[0][1]);
        acc[0][2] = fmaf(A.x, B.z, acc[0][2]); acc[0][3] = fmaf(A.x, B.w, acc[0][3]);
        acc[1][0] = fmaf(A.y, B.x, acc[1][0]); acc[1][1] = fmaf(A.y, B.y, acc[1][1]);
        acc[1][2] = fmaf(A.y, B.z, acc[1][2]); acc[1][3] = fmaf(A.y, B.w, acc[1][3]);
        acc[2][0] = fmaf(A.z, B.x, acc[2][0]); acc[2][1] = fmaf(A.z, B.y, acc[2][1]);
        acc[2][2] = fmaf(A.z, B.z, acc[2][2]); acc[2][3] = fmaf(A.z, B.w, acc[2][3]);
        acc[3][0] = fmaf(A.w, B.x, acc[3][0]); acc[3][1] = fmaf(A.w, B.y, acc[3][1]);
        acc[3][2] = fmaf(A.w, B.z, acc[3][2]); acc[3][3] = fmaf(A.w, B.w, acc[3][3]);
    }
    #pragma unroll
    for (int i = 0; i < 4; ++i) {
        const int r = R0 + 4 * ty + i;
        if (r < N_NODES) {
            f32x4 o;
            o.x = (1.0f - beta) * supT[4 * tx + 0][4 * ty + i] + beta * acc[i][0];
            o.y = (1.0f - beta) * supT[4 * tx + 1][4 * ty + i] + beta * acc[i][1];
            o.z = (1.0f - beta) * supT[4 * tx + 2][4 * ty + i] + beta * acc[i][2];
            o.w = (1.0f - beta) * supT[4 * tx + 3][4 * ty + i] + beta * acc[i][3];
            __builtin_nontemporal_store(o,
                reinterpret_cast<f32x4*>(&out[(size_t)r * D + 4 * tx]));
        }
    }
}

// ===========================================================================
// Tier C fallback: f32 atomic scatter + separate epilogue
// ===========================================================================
__global__ void spmm_atomic_kernel(const int* __restrict__ row,
                                   const int* __restrict__ col,
                                   const float* __restrict__ vals,
                                   const float* __restrict__ H,
                                   float* __restrict__ AH) {
    const long long total = (long long)N_EDGES * 16;
    long long idx = (long long)blockIdx.x * blockDim.x + threadIdx.x;
    if (idx >= total) return;
    const int e   = (int)(idx >> 4);
    const int sub = (int)(idx & 15);
    const int r   = row[e];
    const int c   = col[e];
    const float v = vals[e];
    const float4 h = *reinterpret_cast<const float4*>(&H[(long long)c * D + sub * 4]);
    float* dst = &AH[(long long)r * D + sub * 4];
    atomicAdd(dst + 0, v * h.x);
    atomicAdd(dst + 1, v * h.y);
    atomicAdd(dst + 2, v * h.z);
    atomicAdd(dst + 3, v * h.w);
}

__global__ void __launch_bounds__(256)
gcnii_epilogue_kernel(float* __restrict__ AH_out,
                      const float* __restrict__ H0,
                      const float* __restrict__ W,
                      const float* __restrict__ lamda_p,
                      const float* __restrict__ alpha_p,
                      const int* __restrict__ l_p) {
    __shared__ float Wlds[D * D];
    for (int i = threadIdx.x; i < D * D; i += 256) Wlds[i] = W[i];
    __syncthreads();
    const float alpha = alpha_p[0];
    const float beta  = logf(lamda_p[0] / (float)l_p[0] + 1.0f);
    const int wave = threadIdx.x >> 6;
    const int lane = threadIdx.x & 63;
    const int r = blockIdx.x * 4 + wave;
    if (r >= N_NODES) return;
    const long long base = (long long)r * D;
    const float sup = (1.0f - alpha) * AH_out[base + lane] + alpha * H0[base + lane];
    float acc = 0.0f;
    #pragma unroll
    for (int k = 0; k < D; ++k)
        acc = fmaf(__shfl(sup, k, 64), Wlds[k * D + lane], acc);
    AH_out[base + lane] = (1.0f - beta) * sup + beta * acc;
}

// ===========================================================================
extern "C" void kernel_launch(void* const* d_in, const int* in_sizes, int n_in,
                              void* d_out, int out_size, void* d_ws, size_t ws_size,
                              hipStream_t stream) {
    const int*   row   = (const int*)  d_in[0];
    const int*   col   = (const int*)  d_in[1];
    const float* vals  = (const float*)d_in[2];
    const float* H     = (const float*)d_in[3];
    const float* H0    = (const float*)d_in[4];
    const float* W     = (const float*)d_in[5];
    const float* lamda = (const float*)d_in[6];
    const float* alpha = (const float*)d_in[7];
    const int*   l     = (const int*)  d_in[8];
    float* out = (float*)d_out;

    // Tier A2 layout (4B words):
    //   binCounts : [0, 512)
    //   binBase   : [512, 1024)      (401 used)
    //   binCursor : [1024, 1536)
    //   row_ptr   : [1536, 101568)   (100001 used)
    //   pack4     : [101568, 1701568)
    //   tmp2(u16) : [1701568, 2501568)
    //   tmp4      : [2501568, 4101568)
    //   Hh (fp16) : [4101568, 7301568)
    const size_t neededA2 = (size_t)7301568 * 4;   // 29.2 MB
    const size_t neededA  = (size_t)5000256 * 4;   // 20.0 MB (round-6 path)

    if (ws_size >= neededA2) {
        int*            binCounts = (int*)d_ws;
        int*            binBase   = binCounts + 512;
        int*            binCursor = binCounts + 1024;
        int*            row_ptr   = binCounts + 1536;
        unsigned*       pack      = (unsigned*)(binCounts + 101568);
        unsigned short* tmp2      = (unsigned short*)(binCounts + 1701568);
        unsigned*       tmp4      = (unsigned*)(binCounts + 2501568);
        unsigned short* Hh        = (unsigned short*)(binCounts + 4101568);

        h2half_kernel<<<(N_NODES * D / 4 + 255) / 256, 256, 0, stream>>>(H, Hh);
        hipMemsetAsync(binCounts, 0, NBIN * sizeof(int), stream);
        bin_hist_kernel<<<256, 256, 0, stream>>>(row, binCounts);
        bin_scan_kernel<<<1, 512, 0, stream>>>(binCounts, binBase, binCursor);
        multisplit_kernel<<<(N_EDGES + MS_TILE - 1) / MS_TILE, 256, 0, stream>>>(
            row, col, vals, binCursor, tmp4, tmp2);
        bin_sort_kernel<<<NBIN, 512, 0, stream>>>(binBase, tmp4, tmp2, row_ptr, pack);
        gather_gemm_kernel<<<N_NODES / 32, 256, 0, stream>>>(
            row_ptr, pack, Hh, H0, W, lamda, alpha, l, out);
    } else if (ws_size >= neededA) {
        // round-6 tier A
        int*            counts  = (int*)d_ws;
        int*            row_ptr = counts + 100000;
        int*            totals  = counts + 200064;
        unsigned*       pack    = (unsigned*)(counts + 200192);
        unsigned short* Hh      = (unsigned short*)(counts + 1800256);

        h2half_kernel<<<(N_NODES * D / 4 + 255) / 256, 256, 0, stream>>>(H, Hh);
        hipMemsetAsync(counts, 0, (size_t)N_NODES * sizeof(int), stream);
        hist_kernel<<<(N_EDGES + 255) / 256, 256, 0, stream>>>(row, counts);
        scan1_kernel<<<NCHUNK, 256, 0, stream>>>(counts, row_ptr, totals);
        scan2_kernel<<<NCHUNK, 256, 0, stream>>>(row_ptr, counts, totals);
        scatter_pack_kernel<<<(N_EDGES + 255) / 256, 256, 0, stream>>>(row, col, vals,
                                                                       counts, pack);
        gather_gemm64_kernel<<<(N_NODES + 63) / 64, 256, 0, stream>>>(
            row_ptr, pack, Hh, H0, W, lamda, alpha, l, out);
    } else {
        hipMemsetAsync(out, 0, (size_t)out_size * sizeof(float), stream);
        const long long total = (long long)N_EDGES * 16;
        spmm_atomic_kernel<<<(int)((total + 255) / 256), 256, 0, stream>>>(row, col, vals, H, out);
        gcnii_epilogue_kernel<<<(N_NODES + 3) / 4, 256, 0, stream>>>(out, H0, W,
                                                                     lamda, alpha, l);
    }
}